// Round 19
// baseline (118.793 us; speedup 1.0000x reference)
//
#include <hip/hip_runtime.h>

typedef unsigned short u16;
typedef unsigned int u32;
typedef __bf16 bf16x8 __attribute__((ext_vector_type(8)));
typedef float f32x4 __attribute__((ext_vector_type(4)));
typedef float f32x16 __attribute__((ext_vector_type(16)));
typedef int i32x2 __attribute__((ext_vector_type(2)));
typedef unsigned int u32x4 __attribute__((ext_vector_type(4)));

#define N_TOK 4096
#define DMODEL 1024
#define NH 16
#define DKH 64

__device__ inline u16 f2bf(float f){
  unsigned u = __float_as_uint(f);
  u += 0x7fffu + ((u >> 16) & 1u);
  return (u16)(u >> 16);
}

__device__ inline float fexp2(float x){ return __builtin_amdgcn_exp2f(x); }

// ---------- convert X (f32 -> bf16), vectorized ----------
__global__ __launch_bounds__(256) void k_convX(const float* __restrict__ X, u16* __restrict__ Xb){
  int i = blockIdx.x*256 + threadIdx.x;
  const float4 v = reinterpret_cast<const float4*>(X)[i];
  ushort4 o; o.x=f2bf(v.x); o.y=f2bf(v.y); o.z=f2bf(v.z); o.w=f2bf(v.w);
  reinterpret_cast<ushort4*>(Xb)[i] = o;
}

// ---------- transpose+convert W [1024][2048] f32 -> Wt [2048][1024] bf16 ----------
__global__ __launch_bounds__(256) void k_convW(const float* __restrict__ W, u16* __restrict__ Wt){
  __shared__ float tile[64][65];
  const int bn = blockIdx.x*64;
  const int bk = blockIdx.y*64;
  const int t = threadIdx.x;
  const int c4 = (t & 15)*4;
  const int r  = t >> 4;
  #pragma unroll
  for (int i=0;i<4;i++){
    int k = r + i*16;
    const float4 v = *reinterpret_cast<const float4*>(&W[(size_t)(bk+k)*2048 + bn + c4]);
    tile[k][c4+0]=v.x; tile[k][c4+1]=v.y; tile[k][c4+2]=v.z; tile[k][c4+3]=v.w;
  }
  __syncthreads();
  #pragma unroll
  for (int i=0;i<4;i++){
    int n = r + i*16;
    ushort4 o;
    o.x = f2bf(tile[c4+0][n]);
    o.y = f2bf(tile[c4+1][n]);
    o.z = f2bf(tile[c4+2][n]);
    o.w = f2bf(tile[c4+3][n]);
    *reinterpret_cast<ushort4*>(&Wt[(size_t)(bn+n)*1024 + bk + c4]) = o;
  }
}

// ---------- GEMM v2: BK=64, source-swizzled staging (round-9, proven) ----------
__global__ __launch_bounds__(256) void k_gemm(const u16* __restrict__ A, const u16* __restrict__ B,
                                              u16* __restrict__ kf_g, u16* __restrict__ vf_g){
  __shared__ alignas(16) u16 As[128*64];
  __shared__ alignas(16) u16 Bs[128*64];
  const int bm = blockIdx.y*128, bn = blockIdx.x*128;
  const int tid = threadIdx.x, wid = tid>>6, lane = tid&63;
  const int wr = wid>>1, wc = wid&1;
  const int lr = lane&15, lg = lane>>4;
  f32x4 acc[4][4] = {};

  for (int kk=0; kk<DMODEL; kk+=64){
    __syncthreads();
    #pragma unroll
    for (int i=0;i<4;i++){
      const int chunk = (wid*4+i)*64 + lane;          // 0..1023, 16B each
      const int row = chunk>>3, koc = chunk&7;
      const int swz = koc ^ (row&7);                  // pre-swizzle SOURCE; LDS dest linear
      const u16* ga = A + (size_t)(bm+row)*DMODEL + kk + swz*8;
      const u16* gb = B + (size_t)(bn+row)*DMODEL + kk + swz*8;
      __builtin_amdgcn_global_load_lds((const __attribute__((address_space(1))) void*)ga,
          (__attribute__((address_space(3))) void*)(&As[(size_t)chunk*8]), 16, 0, 0);
      __builtin_amdgcn_global_load_lds((const __attribute__((address_space(1))) void*)gb,
          (__attribute__((address_space(3))) void*)(&Bs[(size_t)chunk*8]), 16, 0, 0);
    }
    asm volatile("s_waitcnt vmcnt(0)" ::: "memory");
    __syncthreads();
    #pragma unroll
    for (int ks=0; ks<2; ks++){
      bf16x8 af[4], bfr[4];
      #pragma unroll
      for (int m=0;m<4;m++){
        const int row = wr*64+m*16+lr, cr = ks*4+lg;
        af[m] = *reinterpret_cast<const bf16x8*>(&As[(size_t)(row*8 + (cr ^ (row&7)))*8]);
      }
      #pragma unroll
      for (int n=0;n<4;n++){
        const int row = wc*64+n*16+lr, cr = ks*4+lg;
        bfr[n] = *reinterpret_cast<const bf16x8*>(&Bs[(size_t)(row*8 + (cr ^ (row&7)))*8]);
      }
      #pragma unroll
      for (int m=0;m<4;m++)
        #pragma unroll
        for (int n=0;n<4;n++)
          acc[m][n] = __builtin_amdgcn_mfma_f32_16x16x32_bf16(af[m], bfr[n], acc[m][n], 0,0,0);
    }
  }

  #pragma unroll
  for (int m=0;m<4;m++){
    const int row0 = bm + wr*64 + m*16 + lg*4;
    #pragma unroll
    for (int n=0;n<4;n++){
      const int c = bn + wc*64 + n*16 + lr;
      if (c < DMODEL){
        const int hh = c>>6, d = c&63;
        const size_t base = ((size_t)hh*512 + (size_t)(row0>>5)*4 + (d>>4))*512;
        #pragma unroll
        for (int r=0;r<4;r++){
          const int row = row0 + r;
          kf_g[base + (size_t)(((row&31) | (((d>>3)&1)<<5)))*8 + (d&7)] = f2bf(acc[m][n][r]);
        }
      } else {
        const int cc = c - DMODEL; const int hh = cc>>6, d = cc&63;
        const size_t base = (((size_t)hh*64 + (row0>>6))*8 + (d>>5)*4 + ((row0>>4)&3))*512
                          + (size_t)(((d&31) | (((row0>>3)&1)<<5)))*8 + (row0&7);
        ushort4 o;
        o.x = f2bf(acc[m][n][0]); o.y = f2bf(acc[m][n][1]);
        o.z = f2bf(acc[m][n][2]); o.w = f2bf(acc[m][n][3]);
        *reinterpret_cast<ushort4*>(&vf_g[base]) = o;
      }
    }
  }
}

// scale a bf16x8 fragment by s (unpack, multiply, repack RNE)
__device__ inline bf16x8 scale_bf8(bf16x8 v, float s){
  u32x4 w = __builtin_bit_cast(u32x4, v);
  u32x4 r;
  #pragma unroll
  for (int i=0;i<4;i++){
    float lo = __uint_as_float(w[i] << 16) * s;
    float hi = __uint_as_float(w[i] & 0xffff0000u) * s;
    u32 p;
    asm("v_cvt_pk_bf16_f32 %0, %1, %2" : "=v"(p) : "v"(lo), "v"(hi));
    r[i] = p;
  }
  return __builtin_bit_cast(bf16x8, r);
}

// ---------- flash attention v18: r14/r18 structure + T5 s_setprio around MFMA clusters.
// 4-wave blocks drift between barriers -> phase diversity -> setprio lets the wave at
// MFMA preempt issue over waves in exp/pack (m191 regime). ----------
__global__ __launch_bounds__(256,2) void k_attn(const u16* __restrict__ kf_g, const u16* __restrict__ vf_g,
                                                float* __restrict__ out){
  __shared__ alignas(16) u16 stg[2][16384];   // [buf][K: chunks 0..15 | V: chunks 16..31]
  const int bid  = blockIdx.x;
  const int xcd  = bid & 7;
  const int slot = bid >> 3;              // 0..63
  const int h    = (xcd<<1) | (slot>>5);  // 2 heads per XCD
  const int qt   = slot & 31;
  const int wid  = threadIdx.x >> 6;
  const int lane = threadIdx.x & 63;
  const int ql   = lane & 31;
  const int q0   = qt*128 + wid*32;
  const u16* __restrict__ Kfh = kf_g + (size_t)h*262144;
  const u16* __restrict__ Vfh = vf_g + (size_t)h*262144;
  const float SC = 0.18033688011112042f;   // log2(e)/sqrt(64)

  bf16x8 qb[4];
  #pragma unroll
  for (int ds=0; ds<4; ds++){
    bf16x8 raw = *reinterpret_cast<const bf16x8*>(&Kfh[(size_t)((q0>>5)*4 + ds)*512 + lane*8]);
    qb[ds] = scale_bf8(raw, SC);
  }

  f32x16 o0 = {}, o1 = {}, lacc = {};

  auto stage = [&](int buf, int t){
    #pragma unroll
    for (int i=0; i<8; i++){
      const int c = wid + i*4;             // 0..31, wave-uniform
      const u16* src = (c < 16)
        ? Kfh + ((size_t)(t*16 + c))*512 + lane*8
        : Vfh + ((size_t)(t*16 + c - 16))*512 + lane*8;
      __builtin_amdgcn_global_load_lds((const __attribute__((address_space(1))) void*)src,
          (__attribute__((address_space(3))) void*)(&stg[buf][(size_t)c*512]), 16, 0, 0);
    }
  };

  stage(0, 0);
  int cur = 0;
  for (int t=0; t<32; ++t){
    asm volatile("s_waitcnt vmcnt(0)" ::: "memory");
    __syncthreads();                       // tile t ready in stg[cur]
    if (t < 31) stage(cur^1, t+1);         // async prefetch next tile

    const u16* kb = &stg[cur][0];

    auto QK = [&](int ss, f32x16& p){
      bf16x8 k0 = *reinterpret_cast<const bf16x8*>(&kb[(size_t)(ss*4+0)*512 + lane*8]);
      bf16x8 k1 = *reinterpret_cast<const bf16x8*>(&kb[(size_t)(ss*4+1)*512 + lane*8]);
      bf16x8 k2 = *reinterpret_cast<const bf16x8*>(&kb[(size_t)(ss*4+2)*512 + lane*8]);
      bf16x8 k3 = *reinterpret_cast<const bf16x8*>(&kb[(size_t)(ss*4+3)*512 + lane*8]);
      f32x16 acc = {};
      __builtin_amdgcn_s_setprio(1);
      acc = __builtin_amdgcn_mfma_f32_32x32x16_bf16(k0, qb[0], acc, 0,0,0);
      acc = __builtin_amdgcn_mfma_f32_32x32x16_bf16(k1, qb[1], acc, 0,0,0);
      acc = __builtin_amdgcn_mfma_f32_32x32x16_bf16(k2, qb[2], acc, 0,0,0);
      acc = __builtin_amdgcn_mfma_f32_32x32x16_bf16(k3, qb[3], acc, 0,0,0);
      __builtin_amdgcn_s_setprio(0);
      p = acc;
    };
    auto SM = [&](f32x16& p, u32* pk){     // exp + lacc + pack (VALU/trans only)
      #pragma unroll
      for (int c=0; c<16; c++) p[c] = fexp2(p[c]);
      lacc += p;
      #pragma unroll
      for (int c2=0; c2<8; c2++){
        u32 a;
        asm("v_cvt_pk_bf16_f32 %0, %1, %2" : "=v"(a) : "v"(p[2*c2]), "v"(p[2*c2+1]));
        pk[c2] = a;
      }
    };
    auto PV = [&](int ss, const u32* pk){
      const int vbase = 8192 + ((ss>>1)*8 + (ss&1)*2)*512;
      bf16x8 va0 = *reinterpret_cast<const bf16x8*>(&kb[(size_t)vbase          + lane*8]);
      bf16x8 va1 = *reinterpret_cast<const bf16x8*>(&kb[(size_t)vbase +   512  + lane*8]);
      bf16x8 vb0 = *reinterpret_cast<const bf16x8*>(&kb[(size_t)vbase + 4*512  + lane*8]);
      bf16x8 vb1 = *reinterpret_cast<const bf16x8*>(&kb[(size_t)vbase + 5*512  + lane*8]);
      #pragma unroll
      for (int t2=0; t2<2; t2++){
        const int base = 4*t2;
        i32x2 r0s = __builtin_amdgcn_permlane32_swap((int)pk[base+0], (int)pk[base+2], false, false);
        i32x2 r1s = __builtin_amdgcn_permlane32_swap((int)pk[base+1], (int)pk[base+3], false, false);
        u32x4 w; w[0] = (u32)r0s[0]; w[1] = (u32)r1s[0]; w[2] = (u32)r0s[1]; w[3] = (u32)r1s[1];
        bf16x8 bt = __builtin_bit_cast(bf16x8, w);
        __builtin_amdgcn_s_setprio(1);
        o0 = __builtin_amdgcn_mfma_f32_32x32x16_bf16(t2 ? va1 : va0, bt, o0, 0,0,0);
        o1 = __builtin_amdgcn_mfma_f32_32x32x16_bf16(t2 ? vb1 : vb0, bt, o1, 0,0,0);
        __builtin_amdgcn_s_setprio(0);
      }
    };

    // 4 ss-steps, 1-deep software pipeline (pA/pB alternate)
    f32x16 pA, pB;
    u32 pkA[8], pkB[8];
    QK(0, pA);
    QK(1, pB);
    SM(pA, pkA);
    PV(0, pkA);
    QK(2, pA);
    SM(pB, pkB);
    PV(1, pkB);
    QK(3, pB);
    SM(pA, pkA);
    PV(2, pkA);
    SM(pB, pkB);
    PV(3, pkB);

    __syncthreads();                       // all waves done reading stg[cur]
    cur ^= 1;
  }

  float lp = (((lacc[0]+lacc[1])+(lacc[2]+lacc[3])) + ((lacc[4]+lacc[5])+(lacc[6]+lacc[7])))
           + (((lacc[8]+lacc[9])+(lacc[10]+lacc[11])) + ((lacc[12]+lacc[13])+(lacc[14]+lacc[15])));
  lp += __shfl_xor(lp, 32, 64);

  const int hi = lane >> 5;
  const float inv = 1.f / lp;
  float* orow = out + (size_t)(q0 + ql)*DMODEL + h*DKH;
  #pragma unroll
  for (int g=0; g<4; g++){
    float4 s0, s1;
    s0.x = o0[4*g+0]*inv; s0.y = o0[4*g+1]*inv; s0.z = o0[4*g+2]*inv; s0.w = o0[4*g+3]*inv;
    s1.x = o1[4*g+0]*inv; s1.y = o1[4*g+1]*inv; s1.z = o1[4*g+2]*inv; s1.w = o1[4*g+3]*inv;
    *reinterpret_cast<float4*>(&orow[      8*g + 4*hi]) = s0;
    *reinterpret_cast<float4*>(&orow[32 +  8*g + 4*hi]) = s1;
  }
}

extern "C" void kernel_launch(void* const* d_in, const int* in_sizes, int n_in,
                              void* d_out, int out_size, void* d_ws, size_t ws_size,
                              hipStream_t stream) {
  const float* X = (const float*)d_in[0];
  const float* W = (const float*)d_in[1];
  float* out = (float*)d_out;
  u16* Xb = (u16*)d_ws;                         //  8 MB
  u16* Wt = Xb + (size_t)N_TOK*DMODEL;          //  4 MB
  u16* Kf = Wt + (size_t)2*DMODEL*DMODEL;       //  8 MB fragment-major K/Q
  u16* Vf = Kf + (size_t)N_TOK*DMODEL;          //  8 MB fragment-major V^T

  k_convX<<<dim3(4096), dim3(256), 0, stream>>>(X, Xb);
  k_convW<<<dim3(32,16), dim3(256), 0, stream>>>(W, Wt);
  k_gemm <<<dim3(16,32), dim3(256), 0, stream>>>(Xb, Wt, Kf, Vf);
  k_attn <<<dim3(512), dim3(256), 0, stream>>>(Kf, Vf, out);
}

// Round 20
// 117.072 us; speedup vs baseline: 1.0147x; 1.0147x over previous
//
#include <hip/hip_runtime.h>

typedef unsigned short u16;
typedef unsigned int u32;
typedef __bf16 bf16x8 __attribute__((ext_vector_type(8)));
typedef float f32x4 __attribute__((ext_vector_type(4)));
typedef float f32x16 __attribute__((ext_vector_type(16)));
typedef int i32x2 __attribute__((ext_vector_type(2)));
typedef unsigned int u32x4 __attribute__((ext_vector_type(4)));

#define N_TOK 4096
#define DMODEL 1024
#define NH 16
#define DKH 64

__device__ inline u16 f2bf(float f){
  unsigned u = __float_as_uint(f);
  u += 0x7fffu + ((u >> 16) & 1u);
  return (u16)(u >> 16);
}

__device__ inline float fexp2(float x){ return __builtin_amdgcn_exp2f(x); }

// ---------- fused conversions: blocks 0..4095 convert X (f32->bf16);
// blocks 4096..4607 transpose+convert W [1024][2048] -> Wt [2048][1024] ----------
__global__ __launch_bounds__(256) void k_conv(const float* __restrict__ X, u16* __restrict__ Xb,
                                              const float* __restrict__ W, u16* __restrict__ Wt){
  if (blockIdx.x < 4096){
    int i = blockIdx.x*256 + threadIdx.x;
    const float4 v = reinterpret_cast<const float4*>(X)[i];
    ushort4 o; o.x=f2bf(v.x); o.y=f2bf(v.y); o.z=f2bf(v.z); o.w=f2bf(v.w);
    reinterpret_cast<ushort4*>(Xb)[i] = o;
    return;
  }
  __shared__ float tile[64][65];
  const int b2 = blockIdx.x - 4096;       // 0..511
  const int bn = (b2 & 31)*64;            // n (2048)
  const int bk = (b2 >> 5)*64;            // k (1024)
  const int t = threadIdx.x;
  const int c4 = (t & 15)*4;
  const int r  = t >> 4;
  #pragma unroll
  for (int i=0;i<4;i++){
    int k = r + i*16;
    const float4 v = *reinterpret_cast<const float4*>(&W[(size_t)(bk+k)*2048 + bn + c4]);
    tile[k][c4+0]=v.x; tile[k][c4+1]=v.y; tile[k][c4+2]=v.z; tile[k][c4+3]=v.w;
  }
  __syncthreads();
  #pragma unroll
  for (int i=0;i<4;i++){
    int n = r + i*16;
    ushort4 o;
    o.x = f2bf(tile[c4+0][n]);
    o.y = f2bf(tile[c4+1][n]);
    o.z = f2bf(tile[c4+2][n]);
    o.w = f2bf(tile[c4+3][n]);
    *reinterpret_cast<ushort4*>(&Wt[(size_t)(bn+n)*1024 + bk + c4]) = o;
  }
}

// ---------- GEMM v2: BK=64, source-swizzled staging (round-9, proven) ----------
__global__ __launch_bounds__(256) void k_gemm(const u16* __restrict__ A, const u16* __restrict__ B,
                                              u16* __restrict__ kf_g, u16* __restrict__ vf_g){
  __shared__ alignas(16) u16 As[128*64];
  __shared__ alignas(16) u16 Bs[128*64];
  const int bm = blockIdx.y*128, bn = blockIdx.x*128;
  const int tid = threadIdx.x, wid = tid>>6, lane = tid&63;
  const int wr = wid>>1, wc = wid&1;
  const int lr = lane&15, lg = lane>>4;
  f32x4 acc[4][4] = {};

  for (int kk=0; kk<DMODEL; kk+=64){
    __syncthreads();
    #pragma unroll
    for (int i=0;i<4;i++){
      const int chunk = (wid*4+i)*64 + lane;          // 0..1023, 16B each
      const int row = chunk>>3, koc = chunk&7;
      const int swz = koc ^ (row&7);                  // pre-swizzle SOURCE; LDS dest linear
      const u16* ga = A + (size_t)(bm+row)*DMODEL + kk + swz*8;
      const u16* gb = B + (size_t)(bn+row)*DMODEL + kk + swz*8;
      __builtin_amdgcn_global_load_lds((const __attribute__((address_space(1))) void*)ga,
          (__attribute__((address_space(3))) void*)(&As[(size_t)chunk*8]), 16, 0, 0);
      __builtin_amdgcn_global_load_lds((const __attribute__((address_space(1))) void*)gb,
          (__attribute__((address_space(3))) void*)(&Bs[(size_t)chunk*8]), 16, 0, 0);
    }
    asm volatile("s_waitcnt vmcnt(0)" ::: "memory");
    __syncthreads();
    #pragma unroll
    for (int ks=0; ks<2; ks++){
      bf16x8 af[4], bfr[4];
      #pragma unroll
      for (int m=0;m<4;m++){
        const int row = wr*64+m*16+lr, cr = ks*4+lg;
        af[m] = *reinterpret_cast<const bf16x8*>(&As[(size_t)(row*8 + (cr ^ (row&7)))*8]);
      }
      #pragma unroll
      for (int n=0;n<4;n++){
        const int row = wc*64+n*16+lr, cr = ks*4+lg;
        bfr[n] = *reinterpret_cast<const bf16x8*>(&Bs[(size_t)(row*8 + (cr ^ (row&7)))*8]);
      }
      #pragma unroll
      for (int m=0;m<4;m++)
        #pragma unroll
        for (int n=0;n<4;n++)
          acc[m][n] = __builtin_amdgcn_mfma_f32_16x16x32_bf16(af[m], bfr[n], acc[m][n], 0,0,0);
    }
  }

  #pragma unroll
  for (int m=0;m<4;m++){
    const int row0 = bm + wr*64 + m*16 + lg*4;
    #pragma unroll
    for (int n=0;n<4;n++){
      const int c = bn + wc*64 + n*16 + lr;
      if (c < DMODEL){
        const int hh = c>>6, d = c&63;
        const size_t base = ((size_t)hh*512 + (size_t)(row0>>5)*4 + (d>>4))*512;
        #pragma unroll
        for (int r=0;r<4;r++){
          const int row = row0 + r;
          kf_g[base + (size_t)(((row&31) | (((d>>3)&1)<<5)))*8 + (d&7)] = f2bf(acc[m][n][r]);
        }
      } else {
        const int cc = c - DMODEL; const int hh = cc>>6, d = cc&63;
        const size_t base = (((size_t)hh*64 + (row0>>6))*8 + (d>>5)*4 + ((row0>>4)&3))*512
                          + (size_t)(((d&31) | (((row0>>3)&1)<<5)))*8 + (row0&7);
        ushort4 o;
        o.x = f2bf(acc[m][n][0]); o.y = f2bf(acc[m][n][1]);
        o.z = f2bf(acc[m][n][2]); o.w = f2bf(acc[m][n][3]);
        *reinterpret_cast<ushort4*>(&vf_g[base]) = o;
      }
    }
  }
}

// scale a bf16x8 fragment by s (unpack, multiply, repack RNE)
__device__ inline bf16x8 scale_bf8(bf16x8 v, float s){
  u32x4 w = __builtin_bit_cast(u32x4, v);
  u32x4 r;
  #pragma unroll
  for (int i=0;i<4;i++){
    float lo = __uint_as_float(w[i] << 16) * s;
    float hi = __uint_as_float(w[i] & 0xffff0000u) * s;
    u32 p;
    asm("v_cvt_pk_bf16_f32 %0, %1, %2" : "=v"(p) : "v"(lo), "v"(hi));
    r[i] = p;
  }
  return __builtin_bit_cast(bf16x8, r);
}

// ---------- flash attention v17 (r18 exact, proven 81.0 us): 128-key LDS tiles,
// 2 blocks/CU, software-pipelined tile body, no setprio. ----------
__global__ __launch_bounds__(256,2) void k_attn(const u16* __restrict__ kf_g, const u16* __restrict__ vf_g,
                                                float* __restrict__ out){
  __shared__ alignas(16) u16 stg[2][16384];   // [buf][K: chunks 0..15 | V: chunks 16..31]
  const int bid  = blockIdx.x;
  const int xcd  = bid & 7;
  const int slot = bid >> 3;              // 0..63
  const int h    = (xcd<<1) | (slot>>5);  // 2 heads per XCD
  const int qt   = slot & 31;
  const int wid  = threadIdx.x >> 6;
  const int lane = threadIdx.x & 63;
  const int ql   = lane & 31;
  const int q0   = qt*128 + wid*32;
  const u16* __restrict__ Kfh = kf_g + (size_t)h*262144;
  const u16* __restrict__ Vfh = vf_g + (size_t)h*262144;
  const float SC = 0.18033688011112042f;   // log2(e)/sqrt(64)

  bf16x8 qb[4];
  #pragma unroll
  for (int ds=0; ds<4; ds++){
    bf16x8 raw = *reinterpret_cast<const bf16x8*>(&Kfh[(size_t)((q0>>5)*4 + ds)*512 + lane*8]);
    qb[ds] = scale_bf8(raw, SC);
  }

  f32x16 o0 = {}, o1 = {}, lacc = {};

  auto stage = [&](int buf, int t){
    #pragma unroll
    for (int i=0; i<8; i++){
      const int c = wid + i*4;             // 0..31, wave-uniform
      const u16* src = (c < 16)
        ? Kfh + ((size_t)(t*16 + c))*512 + lane*8
        : Vfh + ((size_t)(t*16 + c - 16))*512 + lane*8;
      __builtin_amdgcn_global_load_lds((const __attribute__((address_space(1))) void*)src,
          (__attribute__((address_space(3))) void*)(&stg[buf][(size_t)c*512]), 16, 0, 0);
    }
  };

  stage(0, 0);
  int cur = 0;
  for (int t=0; t<32; ++t){
    asm volatile("s_waitcnt vmcnt(0)" ::: "memory");
    __syncthreads();                       // tile t ready in stg[cur]
    if (t < 31) stage(cur^1, t+1);         // async prefetch next tile

    const u16* kb = &stg[cur][0];

    auto QK = [&](int ss, f32x16& p){
      bf16x8 k0 = *reinterpret_cast<const bf16x8*>(&kb[(size_t)(ss*4+0)*512 + lane*8]);
      bf16x8 k1 = *reinterpret_cast<const bf16x8*>(&kb[(size_t)(ss*4+1)*512 + lane*8]);
      bf16x8 k2 = *reinterpret_cast<const bf16x8*>(&kb[(size_t)(ss*4+2)*512 + lane*8]);
      bf16x8 k3 = *reinterpret_cast<const bf16x8*>(&kb[(size_t)(ss*4+3)*512 + lane*8]);
      f32x16 acc = {};
      acc = __builtin_amdgcn_mfma_f32_32x32x16_bf16(k0, qb[0], acc, 0,0,0);
      acc = __builtin_amdgcn_mfma_f32_32x32x16_bf16(k1, qb[1], acc, 0,0,0);
      acc = __builtin_amdgcn_mfma_f32_32x32x16_bf16(k2, qb[2], acc, 0,0,0);
      acc = __builtin_amdgcn_mfma_f32_32x32x16_bf16(k3, qb[3], acc, 0,0,0);
      p = acc;
    };
    auto SM = [&](f32x16& p, u32* pk){     // exp + lacc + pack (VALU/trans only)
      #pragma unroll
      for (int c=0; c<16; c++) p[c] = fexp2(p[c]);
      lacc += p;
      #pragma unroll
      for (int c2=0; c2<8; c2++){
        u32 a;
        asm("v_cvt_pk_bf16_f32 %0, %1, %2" : "=v"(a) : "v"(p[2*c2]), "v"(p[2*c2+1]));
        pk[c2] = a;
      }
    };
    auto PV = [&](int ss, const u32* pk){
      const int vbase = 8192 + ((ss>>1)*8 + (ss&1)*2)*512;
      bf16x8 va0 = *reinterpret_cast<const bf16x8*>(&kb[(size_t)vbase          + lane*8]);
      bf16x8 va1 = *reinterpret_cast<const bf16x8*>(&kb[(size_t)vbase +   512  + lane*8]);
      bf16x8 vb0 = *reinterpret_cast<const bf16x8*>(&kb[(size_t)vbase + 4*512  + lane*8]);
      bf16x8 vb1 = *reinterpret_cast<const bf16x8*>(&kb[(size_t)vbase + 5*512  + lane*8]);
      #pragma unroll
      for (int t2=0; t2<2; t2++){
        const int base = 4*t2;
        i32x2 r0s = __builtin_amdgcn_permlane32_swap((int)pk[base+0], (int)pk[base+2], false, false);
        i32x2 r1s = __builtin_amdgcn_permlane32_swap((int)pk[base+1], (int)pk[base+3], false, false);
        u32x4 w; w[0] = (u32)r0s[0]; w[1] = (u32)r1s[0]; w[2] = (u32)r0s[1]; w[3] = (u32)r1s[1];
        bf16x8 bt = __builtin_bit_cast(bf16x8, w);
        o0 = __builtin_amdgcn_mfma_f32_32x32x16_bf16(t2 ? va1 : va0, bt, o0, 0,0,0);
        o1 = __builtin_amdgcn_mfma_f32_32x32x16_bf16(t2 ? vb1 : vb0, bt, o1, 0,0,0);
      }
    };

    // 4 ss-steps, 1-deep software pipeline (pA/pB alternate)
    f32x16 pA, pB;
    u32 pkA[8], pkB[8];
    QK(0, pA);
    QK(1, pB);
    SM(pA, pkA);
    PV(0, pkA);
    QK(2, pA);
    SM(pB, pkB);
    PV(1, pkB);
    QK(3, pB);
    SM(pA, pkA);
    PV(2, pkA);
    SM(pB, pkB);
    PV(3, pkB);

    __syncthreads();                       // all waves done reading stg[cur]
    cur ^= 1;
  }

  float lp = (((lacc[0]+lacc[1])+(lacc[2]+lacc[3])) + ((lacc[4]+lacc[5])+(lacc[6]+lacc[7])))
           + (((lacc[8]+lacc[9])+(lacc[10]+lacc[11])) + ((lacc[12]+lacc[13])+(lacc[14]+lacc[15])));
  lp += __shfl_xor(lp, 32, 64);

  const int hi = lane >> 5;
  const float inv = 1.f / lp;
  float* orow = out + (size_t)(q0 + ql)*DMODEL + h*DKH;
  #pragma unroll
  for (int g=0; g<4; g++){
    float4 s0, s1;
    s0.x = o0[4*g+0]*inv; s0.y = o0[4*g+1]*inv; s0.z = o0[4*g+2]*inv; s0.w = o0[4*g+3]*inv;
    s1.x = o1[4*g+0]*inv; s1.y = o1[4*g+1]*inv; s1.z = o1[4*g+2]*inv; s1.w = o1[4*g+3]*inv;
    *reinterpret_cast<float4*>(&orow[      8*g + 4*hi]) = s0;
    *reinterpret_cast<float4*>(&orow[32 +  8*g + 4*hi]) = s1;
  }
}

extern "C" void kernel_launch(void* const* d_in, const int* in_sizes, int n_in,
                              void* d_out, int out_size, void* d_ws, size_t ws_size,
                              hipStream_t stream) {
  const float* X = (const float*)d_in[0];
  const float* W = (const float*)d_in[1];
  float* out = (float*)d_out;
  u16* Xb = (u16*)d_ws;                         //  8 MB
  u16* Wt = Xb + (size_t)N_TOK*DMODEL;          //  4 MB
  u16* Kf = Wt + (size_t)2*DMODEL*DMODEL;       //  8 MB fragment-major K/Q
  u16* Vf = Kf + (size_t)N_TOK*DMODEL;          //  8 MB fragment-major V^T

  k_conv <<<dim3(4608), dim3(256), 0, stream>>>(X, Xb, W, Wt);
  k_gemm <<<dim3(16,32), dim3(256), 0, stream>>>(Xb, Wt, Kf, Vf);
  k_attn <<<dim3(512), dim3(256), 0, stream>>>(Kf, Vf, out);
}

// Round 21
// 114.657 us; speedup vs baseline: 1.0361x; 1.0211x over previous
//
#include <hip/hip_runtime.h>

typedef unsigned short u16;
typedef unsigned int u32;
typedef __bf16 bf16x8 __attribute__((ext_vector_type(8)));
typedef float f32x4 __attribute__((ext_vector_type(4)));
typedef float f32x16 __attribute__((ext_vector_type(16)));
typedef int i32x2 __attribute__((ext_vector_type(2)));
typedef unsigned int u32x4 __attribute__((ext_vector_type(4)));

#define N_TOK 4096
#define DMODEL 1024
#define NH 16
#define DKH 64

__device__ inline u16 f2bf(float f){
  unsigned u = __float_as_uint(f);
  u += 0x7fffu + ((u >> 16) & 1u);
  return (u16)(u >> 16);
}

__device__ inline float fexp2(float x){ return __builtin_amdgcn_exp2f(x); }

// ---------- fused conversions: blocks 0..4095 convert X (f32->bf16);
// blocks 4096..4607 transpose+convert W [1024][2048] -> Wt [2048][1024] ----------
__global__ __launch_bounds__(256) void k_conv(const float* __restrict__ X, u16* __restrict__ Xb,
                                              const float* __restrict__ W, u16* __restrict__ Wt){
  if (blockIdx.x < 4096){
    int i = blockIdx.x*256 + threadIdx.x;
    const float4 v = reinterpret_cast<const float4*>(X)[i];
    ushort4 o; o.x=f2bf(v.x); o.y=f2bf(v.y); o.z=f2bf(v.z); o.w=f2bf(v.w);
    reinterpret_cast<ushort4*>(Xb)[i] = o;
    return;
  }
  __shared__ float tile[64][65];
  const int b2 = blockIdx.x - 4096;       // 0..511
  const int bn = (b2 & 31)*64;            // n (2048)
  const int bk = (b2 >> 5)*64;            // k (1024)
  const int t = threadIdx.x;
  const int c4 = (t & 15)*4;
  const int r  = t >> 4;
  #pragma unroll
  for (int i=0;i<4;i++){
    int k = r + i*16;
    const float4 v = *reinterpret_cast<const float4*>(&W[(size_t)(bk+k)*2048 + bn + c4]);
    tile[k][c4+0]=v.x; tile[k][c4+1]=v.y; tile[k][c4+2]=v.z; tile[k][c4+3]=v.w;
  }
  __syncthreads();
  #pragma unroll
  for (int i=0;i<4;i++){
    int n = r + i*16;
    ushort4 o;
    o.x = f2bf(tile[c4+0][n]);
    o.y = f2bf(tile[c4+1][n]);
    o.z = f2bf(tile[c4+2][n]);
    o.w = f2bf(tile[c4+3][n]);
    *reinterpret_cast<ushort4*>(&Wt[(size_t)(bn+n)*1024 + bk + c4]) = o;
  }
}

// ---------- GEMM v3: BK=64 source-swizzled staging (proven) + LDS-bounce Kf epilogue.
// K-half blocks (blockIdx.x<8): scatter acc->LDS bf16 tile, then coalesced 16B Kf stores.
// V-half blocks keep the proven ushort4 scatter. ----------
struct GemmShm {
  union {
    struct { u16 As[128*64]; u16 Bs[128*64]; };   // 32 KB (staging)
    u16 LB[128*136];                              // 34.8 KB (epilogue bounce, 136-pad)
  };
};

__global__ __launch_bounds__(256) void k_gemm(const u16* __restrict__ A, const u16* __restrict__ B,
                                              u16* __restrict__ kf_g, u16* __restrict__ vf_g){
  __shared__ alignas(16) GemmShm shm;
  const int bm = blockIdx.y*128, bn = blockIdx.x*128;
  const int tid = threadIdx.x, wid = tid>>6, lane = tid&63;
  const int wr = wid>>1, wc = wid&1;
  const int lr = lane&15, lg = lane>>4;
  f32x4 acc[4][4] = {};

  for (int kk=0; kk<DMODEL; kk+=64){
    __syncthreads();
    #pragma unroll
    for (int i=0;i<4;i++){
      const int chunk = (wid*4+i)*64 + lane;          // 0..1023, 16B each
      const int row = chunk>>3, koc = chunk&7;
      const int swz = koc ^ (row&7);                  // pre-swizzle SOURCE; LDS dest linear
      const u16* ga = A + (size_t)(bm+row)*DMODEL + kk + swz*8;
      const u16* gb = B + (size_t)(bn+row)*DMODEL + kk + swz*8;
      __builtin_amdgcn_global_load_lds((const __attribute__((address_space(1))) void*)ga,
          (__attribute__((address_space(3))) void*)(&shm.As[(size_t)chunk*8]), 16, 0, 0);
      __builtin_amdgcn_global_load_lds((const __attribute__((address_space(1))) void*)gb,
          (__attribute__((address_space(3))) void*)(&shm.Bs[(size_t)chunk*8]), 16, 0, 0);
    }
    asm volatile("s_waitcnt vmcnt(0)" ::: "memory");
    __syncthreads();
    #pragma unroll
    for (int ks=0; ks<2; ks++){
      bf16x8 af[4], bfr[4];
      #pragma unroll
      for (int m=0;m<4;m++){
        const int row = wr*64+m*16+lr, cr = ks*4+lg;
        af[m] = *reinterpret_cast<const bf16x8*>(&shm.As[(size_t)(row*8 + (cr ^ (row&7)))*8]);
      }
      #pragma unroll
      for (int n=0;n<4;n++){
        const int row = wc*64+n*16+lr, cr = ks*4+lg;
        bfr[n] = *reinterpret_cast<const bf16x8*>(&shm.Bs[(size_t)(row*8 + (cr ^ (row&7)))*8]);
      }
      #pragma unroll
      for (int m=0;m<4;m++)
        #pragma unroll
        for (int n=0;n<4;n++)
          acc[m][n] = __builtin_amdgcn_mfma_f32_16x16x32_bf16(af[m], bfr[n], acc[m][n], 0,0,0);
    }
  }

  if (bn < DMODEL){
    // ---- K-half: LDS bounce -> coalesced 16B Kf stores ----
    __syncthreads();                       // staging reads done before LB overwrite
    #pragma unroll
    for (int m=0;m<4;m++){
      const int row0 = wr*64 + m*16 + lg*4;
      #pragma unroll
      for (int n=0;n<4;n++){
        const int col = wc*64 + n*16 + lr;
        #pragma unroll
        for (int r=0;r<4;r++)
          shm.LB[(size_t)(row0+r)*136 + col] = f2bf(acc[m][n][r]);
      }
    }
    __syncthreads();
    // 2048 chunks of 16B: chunk = (hh2, kb_l, ds, l); consecutive tid -> consecutive l
    #pragma unroll
    for (int i=0;i<8;i++){
      const int chunk = i*256 + tid;
      const int hh2  = chunk >> 10;
      const int rem  = chunk & 1023;
      const int kb_l = rem >> 8;
      const int ds   = (rem >> 6) & 3;
      const int l    = rem & 63;
      const int row_local = kb_l*32 + (l & 31);
      const int colbase   = hh2*64 + ds*16 + ((l >> 5) << 3);
      u32x4 v = *reinterpret_cast<const u32x4*>(&shm.LB[(size_t)row_local*136 + colbase]);
      const int hh = (bn>>6) + hh2;
      const int kb = (bm>>5) + kb_l;
      u16* dst = kf_g + (size_t)hh*262144 + ((size_t)kb*4 + ds)*512 + (size_t)l*8;
      *reinterpret_cast<u32x4*>(dst) = v;
    }
  } else {
    // ---- V-half: proven ushort4 scatter ----
    #pragma unroll
    for (int m=0;m<4;m++){
      const int row0 = bm + wr*64 + m*16 + lg*4;
      #pragma unroll
      for (int n=0;n<4;n++){
        const int c = bn + wc*64 + n*16 + lr;
        const int cc = c - DMODEL; const int hh = cc>>6, d = cc&63;
        const size_t base = (((size_t)hh*64 + (row0>>6))*8 + (d>>5)*4 + ((row0>>4)&3))*512
                          + (size_t)(((d&31) | (((row0>>3)&1)<<5)))*8 + (row0&7);
        ushort4 o;
        o.x = f2bf(acc[m][n][0]); o.y = f2bf(acc[m][n][1]);
        o.z = f2bf(acc[m][n][2]); o.w = f2bf(acc[m][n][3]);
        *reinterpret_cast<ushort4*>(&vf_g[base]) = o;
      }
    }
  }
}

// scale a bf16x8 fragment by s (unpack, multiply, repack RNE)
__device__ inline bf16x8 scale_bf8(bf16x8 v, float s){
  u32x4 w = __builtin_bit_cast(u32x4, v);
  u32x4 r;
  #pragma unroll
  for (int i=0;i<4;i++){
    float lo = __uint_as_float(w[i] << 16) * s;
    float hi = __uint_as_float(w[i] & 0xffff0000u) * s;
    u32 p;
    asm("v_cvt_pk_bf16_f32 %0, %1, %2" : "=v"(p) : "v"(lo), "v"(hi));
    r[i] = p;
  }
  return __builtin_bit_cast(bf16x8, r);
}

// ---------- flash attention (r18 exact, proven 81.0 us): 128-key LDS tiles,
// 2 blocks/CU, software-pipelined tile body. ----------
__global__ __launch_bounds__(256,2) void k_attn(const u16* __restrict__ kf_g, const u16* __restrict__ vf_g,
                                                float* __restrict__ out){
  __shared__ alignas(16) u16 stg[2][16384];   // [buf][K: chunks 0..15 | V: chunks 16..31]
  const int bid  = blockIdx.x;
  const int xcd  = bid & 7;
  const int slot = bid >> 3;              // 0..63
  const int h    = (xcd<<1) | (slot>>5);  // 2 heads per XCD
  const int qt   = slot & 31;
  const int wid  = threadIdx.x >> 6;
  const int lane = threadIdx.x & 63;
  const int ql   = lane & 31;
  const int q0   = qt*128 + wid*32;
  const u16* __restrict__ Kfh = kf_g + (size_t)h*262144;
  const u16* __restrict__ Vfh = vf_g + (size_t)h*262144;
  const float SC = 0.18033688011112042f;   // log2(e)/sqrt(64)

  bf16x8 qb[4];
  #pragma unroll
  for (int ds=0; ds<4; ds++){
    bf16x8 raw = *reinterpret_cast<const bf16x8*>(&Kfh[(size_t)((q0>>5)*4 + ds)*512 + lane*8]);
    qb[ds] = scale_bf8(raw, SC);
  }

  f32x16 o0 = {}, o1 = {}, lacc = {};

  auto stage = [&](int buf, int t){
    #pragma unroll
    for (int i=0; i<8; i++){
      const int c = wid + i*4;             // 0..31, wave-uniform
      const u16* src = (c < 16)
        ? Kfh + ((size_t)(t*16 + c))*512 + lane*8
        : Vfh + ((size_t)(t*16 + c - 16))*512 + lane*8;
      __builtin_amdgcn_global_load_lds((const __attribute__((address_space(1))) void*)src,
          (__attribute__((address_space(3))) void*)(&stg[buf][(size_t)c*512]), 16, 0, 0);
    }
  };

  stage(0, 0);
  int cur = 0;
  for (int t=0; t<32; ++t){
    asm volatile("s_waitcnt vmcnt(0)" ::: "memory");
    __syncthreads();                       // tile t ready in stg[cur]
    if (t < 31) stage(cur^1, t+1);         // async prefetch next tile

    const u16* kb = &stg[cur][0];

    auto QK = [&](int ss, f32x16& p){
      bf16x8 k0 = *reinterpret_cast<const bf16x8*>(&kb[(size_t)(ss*4+0)*512 + lane*8]);
      bf16x8 k1 = *reinterpret_cast<const bf16x8*>(&kb[(size_t)(ss*4+1)*512 + lane*8]);
      bf16x8 k2 = *reinterpret_cast<const bf16x8*>(&kb[(size_t)(ss*4+2)*512 + lane*8]);
      bf16x8 k3 = *reinterpret_cast<const bf16x8*>(&kb[(size_t)(ss*4+3)*512 + lane*8]);
      f32x16 acc = {};
      acc = __builtin_amdgcn_mfma_f32_32x32x16_bf16(k0, qb[0], acc, 0,0,0);
      acc = __builtin_amdgcn_mfma_f32_32x32x16_bf16(k1, qb[1], acc, 0,0,0);
      acc = __builtin_amdgcn_mfma_f32_32x32x16_bf16(k2, qb[2], acc, 0,0,0);
      acc = __builtin_amdgcn_mfma_f32_32x32x16_bf16(k3, qb[3], acc, 0,0,0);
      p = acc;
    };
    auto SM = [&](f32x16& p, u32* pk){     // exp + lacc + pack (VALU/trans only)
      #pragma unroll
      for (int c=0; c<16; c++) p[c] = fexp2(p[c]);
      lacc += p;
      #pragma unroll
      for (int c2=0; c2<8; c2++){
        u32 a;
        asm("v_cvt_pk_bf16_f32 %0, %1, %2" : "=v"(a) : "v"(p[2*c2]), "v"(p[2*c2+1]));
        pk[c2] = a;
      }
    };
    auto PV = [&](int ss, const u32* pk){
      const int vbase = 8192 + ((ss>>1)*8 + (ss&1)*2)*512;
      bf16x8 va0 = *reinterpret_cast<const bf16x8*>(&kb[(size_t)vbase          + lane*8]);
      bf16x8 va1 = *reinterpret_cast<const bf16x8*>(&kb[(size_t)vbase +   512  + lane*8]);
      bf16x8 vb0 = *reinterpret_cast<const bf16x8*>(&kb[(size_t)vbase + 4*512  + lane*8]);
      bf16x8 vb1 = *reinterpret_cast<const bf16x8*>(&kb[(size_t)vbase + 5*512  + lane*8]);
      #pragma unroll
      for (int t2=0; t2<2; t2++){
        const int base = 4*t2;
        i32x2 r0s = __builtin_amdgcn_permlane32_swap((int)pk[base+0], (int)pk[base+2], false, false);
        i32x2 r1s = __builtin_amdgcn_permlane32_swap((int)pk[base+1], (int)pk[base+3], false, false);
        u32x4 w; w[0] = (u32)r0s[0]; w[1] = (u32)r1s[0]; w[2] = (u32)r0s[1]; w[3] = (u32)r1s[1];
        bf16x8 bt = __builtin_bit_cast(bf16x8, w);
        o0 = __builtin_amdgcn_mfma_f32_32x32x16_bf16(t2 ? va1 : va0, bt, o0, 0,0,0);
        o1 = __builtin_amdgcn_mfma_f32_32x32x16_bf16(t2 ? vb1 : vb0, bt, o1, 0,0,0);
      }
    };

    // 4 ss-steps, 1-deep software pipeline (pA/pB alternate)
    f32x16 pA, pB;
    u32 pkA[8], pkB[8];
    QK(0, pA);
    QK(1, pB);
    SM(pA, pkA);
    PV(0, pkA);
    QK(2, pA);
    SM(pB, pkB);
    PV(1, pkB);
    QK(3, pB);
    SM(pA, pkA);
    PV(2, pkA);
    SM(pB, pkB);
    PV(3, pkB);

    __syncthreads();                       // all waves done reading stg[cur]
    cur ^= 1;
  }

  float lp = (((lacc[0]+lacc[1])+(lacc[2]+lacc[3])) + ((lacc[4]+lacc[5])+(lacc[6]+lacc[7])))
           + (((lacc[8]+lacc[9])+(lacc[10]+lacc[11])) + ((lacc[12]+lacc[13])+(lacc[14]+lacc[15])));
  lp += __shfl_xor(lp, 32, 64);

  const int hi = lane >> 5;
  const float inv = 1.f / lp;
  float* orow = out + (size_t)(q0 + ql)*DMODEL + h*DKH;
  #pragma unroll
  for (int g=0; g<4; g++){
    float4 s0, s1;
    s0.x = o0[4*g+0]*inv; s0.y = o0[4*g+1]*inv; s0.z = o0[4*g+2]*inv; s0.w = o0[4*g+3]*inv;
    s1.x = o1[4*g+0]*inv; s1.y = o1[4*g+1]*inv; s1.z = o1[4*g+2]*inv; s1.w = o1[4*g+3]*inv;
    *reinterpret_cast<float4*>(&orow[      8*g + 4*hi]) = s0;
    *reinterpret_cast<float4*>(&orow[32 +  8*g + 4*hi]) = s1;
  }
}

extern "C" void kernel_launch(void* const* d_in, const int* in_sizes, int n_in,
                              void* d_out, int out_size, void* d_ws, size_t ws_size,
                              hipStream_t stream) {
  const float* X = (const float*)d_in[0];
  const float* W = (const float*)d_in[1];
  float* out = (float*)d_out;
  u16* Xb = (u16*)d_ws;                         //  8 MB
  u16* Wt = Xb + (size_t)N_TOK*DMODEL;          //  4 MB
  u16* Kf = Wt + (size_t)2*DMODEL*DMODEL;       //  8 MB fragment-major K/Q
  u16* Vf = Kf + (size_t)N_TOK*DMODEL;          //  8 MB fragment-major V^T

  k_conv <<<dim3(4608), dim3(256), 0, stream>>>(X, Xb, W, Wt);
  k_gemm <<<dim3(16,32), dim3(256), 0, stream>>>(Xb, Wt, Kf, Vf);
  k_attn <<<dim3(512), dim3(256), 0, stream>>>(Kf, Vf, out);
}

// Round 22
// 113.632 us; speedup vs baseline: 1.0454x; 1.0090x over previous
//
#include <hip/hip_runtime.h>

typedef unsigned short u16;
typedef unsigned int u32;
typedef __bf16 bf16x8 __attribute__((ext_vector_type(8)));
typedef float f32x4 __attribute__((ext_vector_type(4)));
typedef float f32x16 __attribute__((ext_vector_type(16)));
typedef int i32x2 __attribute__((ext_vector_type(2)));
typedef unsigned int u32x4 __attribute__((ext_vector_type(4)));

#define N_TOK 4096
#define DMODEL 1024
#define NH 16
#define DKH 64

__device__ inline u16 f2bf(float f){
  unsigned u = __float_as_uint(f);
  u += 0x7fffu + ((u >> 16) & 1u);
  return (u16)(u >> 16);
}

__device__ inline float fexp2(float x){ return __builtin_amdgcn_exp2f(x); }

// ---------- fused conversions: blocks 0..4095 convert X (f32->bf16);
// blocks 4096..4607 transpose+convert W [1024][2048] -> Wt [2048][1024] ----------
__global__ __launch_bounds__(256) void k_conv(const float* __restrict__ X, u16* __restrict__ Xb,
                                              const float* __restrict__ W, u16* __restrict__ Wt){
  if (blockIdx.x < 4096){
    int i = blockIdx.x*256 + threadIdx.x;
    const float4 v = reinterpret_cast<const float4*>(X)[i];
    ushort4 o; o.x=f2bf(v.x); o.y=f2bf(v.y); o.z=f2bf(v.z); o.w=f2bf(v.w);
    reinterpret_cast<ushort4*>(Xb)[i] = o;
    return;
  }
  __shared__ float tile[64][65];
  const int b2 = blockIdx.x - 4096;       // 0..511
  const int bn = (b2 & 31)*64;            // n (2048)
  const int bk = (b2 >> 5)*64;            // k (1024)
  const int t = threadIdx.x;
  const int c4 = (t & 15)*4;
  const int r  = t >> 4;
  #pragma unroll
  for (int i=0;i<4;i++){
    int k = r + i*16;
    const float4 v = *reinterpret_cast<const float4*>(&W[(size_t)(bk+k)*2048 + bn + c4]);
    tile[k][c4+0]=v.x; tile[k][c4+1]=v.y; tile[k][c4+2]=v.z; tile[k][c4+3]=v.w;
  }
  __syncthreads();
  #pragma unroll
  for (int i=0;i<4;i++){
    int n = r + i*16;
    ushort4 o;
    o.x = f2bf(tile[c4+0][n]);
    o.y = f2bf(tile[c4+1][n]);
    o.z = f2bf(tile[c4+2][n]);
    o.w = f2bf(tile[c4+3][n]);
    *reinterpret_cast<ushort4*>(&Wt[(size_t)(bn+n)*1024 + bk + c4]) = o;
  }
}

// ---------- GEMM v4: BK=64 source-swizzled staging, DOUBLE-BUFFERED (attn-style overlap),
// LDS-bounce epilogues for BOTH halves (K: row-major LB, V: transposed LB). ----------
struct GemmShm {
  union {
    u16 stg[2][16384];    // [buf][As: 0..8191 | Bs: 8192..16383]  (64 KB)
    u16 LB[128*136];      // epilogue bounce (34.8 KB)
  };
};

__global__ __launch_bounds__(256) void k_gemm(const u16* __restrict__ A, const u16* __restrict__ B,
                                              u16* __restrict__ kf_g, u16* __restrict__ vf_g){
  __shared__ alignas(16) GemmShm shm;
  const int bm = blockIdx.y*128, bn = blockIdx.x*128;
  const int tid = threadIdx.x, wid = tid>>6, lane = tid&63;
  const int wr = wid>>1, wc = wid&1;
  const int lr = lane&15, lg = lane>>4;
  f32x4 acc[4][4] = {};

  auto stage = [&](int buf, int kk){
    #pragma unroll
    for (int i=0;i<4;i++){
      const int chunk = (wid*4+i)*64 + lane;          // 0..1023, 16B each
      const int row = chunk>>3, koc = chunk&7;
      const int swz = koc ^ (row&7);                  // pre-swizzle SOURCE; LDS dest linear
      const u16* ga = A + (size_t)(bm+row)*DMODEL + kk + swz*8;
      const u16* gb = B + (size_t)(bn+row)*DMODEL + kk + swz*8;
      __builtin_amdgcn_global_load_lds((const __attribute__((address_space(1))) void*)ga,
          (__attribute__((address_space(3))) void*)(&shm.stg[buf][(size_t)chunk*8]), 16, 0, 0);
      __builtin_amdgcn_global_load_lds((const __attribute__((address_space(1))) void*)gb,
          (__attribute__((address_space(3))) void*)(&shm.stg[buf][8192 + (size_t)chunk*8]), 16, 0, 0);
    }
  };

  stage(0, 0);
  int cur = 0;
  for (int t=0; t<16; ++t){
    asm volatile("s_waitcnt vmcnt(0)" ::: "memory");
    __syncthreads();                       // tile t ready in stg[cur]
    if (t < 15) stage(cur^1, (t+1)*64);    // async prefetch next K-tile
    const u16* As = &shm.stg[cur][0];
    const u16* Bs = &shm.stg[cur][8192];
    #pragma unroll
    for (int ks=0; ks<2; ks++){
      bf16x8 af[4], bfr[4];
      #pragma unroll
      for (int m=0;m<4;m++){
        const int row = wr*64+m*16+lr, cr = ks*4+lg;
        af[m] = *reinterpret_cast<const bf16x8*>(&As[(size_t)(row*8 + (cr ^ (row&7)))*8]);
      }
      #pragma unroll
      for (int n=0;n<4;n++){
        const int row = wc*64+n*16+lr, cr = ks*4+lg;
        bfr[n] = *reinterpret_cast<const bf16x8*>(&Bs[(size_t)(row*8 + (cr ^ (row&7)))*8]);
      }
      #pragma unroll
      for (int m=0;m<4;m++)
        #pragma unroll
        for (int n=0;n<4;n++)
          acc[m][n] = __builtin_amdgcn_mfma_f32_16x16x32_bf16(af[m], bfr[n], acc[m][n], 0,0,0);
    }
    __syncthreads();                       // all waves done reading stg[cur]
    cur ^= 1;
  }

  if (bn < DMODEL){
    // ---- K-half: LDS bounce (row-major) -> coalesced 16B Kf stores ----
    #pragma unroll
    for (int m=0;m<4;m++){
      const int row0 = wr*64 + m*16 + lg*4;
      #pragma unroll
      for (int n=0;n<4;n++){
        const int col = wc*64 + n*16 + lr;
        #pragma unroll
        for (int r=0;r<4;r++)
          shm.LB[(size_t)(row0+r)*136 + col] = f2bf(acc[m][n][r]);
      }
    }
    __syncthreads();
    #pragma unroll
    for (int i=0;i<8;i++){
      const int chunk = i*256 + tid;       // 0..2047 16B-units
      const int hh2  = chunk >> 10;
      const int rem  = chunk & 1023;
      const int kb_l = rem >> 8;
      const int ds   = (rem >> 6) & 3;
      const int l    = rem & 63;
      const int row_local = kb_l*32 + (l & 31);
      const int colbase   = hh2*64 + ds*16 + ((l >> 5) << 3);
      u32x4 v = *reinterpret_cast<const u32x4*>(&shm.LB[(size_t)row_local*136 + colbase]);
      const int hh = (bn>>6) + hh2;
      const int kb = (bm>>5) + kb_l;
      u16* dst = kf_g + (size_t)hh*262144 + ((size_t)kb*4 + ds)*512 + (size_t)l*8;
      *reinterpret_cast<u32x4*>(dst) = v;
    }
  } else {
    // ---- V-half: LDS bounce TRANSPOSED (LB[col][row]) -> coalesced 16B Vf stores ----
    #pragma unroll
    for (int m=0;m<4;m++){
      const int row0 = wr*64 + m*16 + lg*4;
      #pragma unroll
      for (int n=0;n<4;n++){
        const int col = wc*64 + n*16 + lr;  // cc_local = d-direction
        ushort4 o;
        o.x = f2bf(acc[m][n][0]); o.y = f2bf(acc[m][n][1]);
        o.z = f2bf(acc[m][n][2]); o.w = f2bf(acc[m][n][3]);
        *reinterpret_cast<ushort4*>(&shm.LB[(size_t)col*136 + row0]) = o;
      }
    }
    __syncthreads();
    const int hh_base = (bn - DMODEL) >> 6;
    const int kb_base = bm >> 6;
    #pragma unroll
    for (int i=0;i<8;i++){
      const int unit = i*256 + tid;        // 0..2047 16B-units
      const int l  = unit & 63;
      const int c5 = unit >> 6;            // 0..31
      const int hh2  = c5 >> 4;
      const int kb_l = (c5 >> 3) & 1;
      const int dt   = (c5 >> 2) & 1;
      const int tt   = c5 & 3;
      const int col_local = hh2*64 + dt*32 + (l & 31);
      const int row_base  = kb_l*64 + tt*16 + ((l >> 5) << 3);
      u32x4 v = *reinterpret_cast<const u32x4*>(&shm.LB[(size_t)col_local*136 + row_base]);
      u16* dst = vf_g + ((size_t)((hh_base+hh2)*64 + kb_base + kb_l)*8 + dt*4 + tt)*512 + (size_t)l*8;
      *reinterpret_cast<u32x4*>(dst) = v;
    }
  }
}

// scale a bf16x8 fragment by s (unpack, multiply, repack RNE)
__device__ inline bf16x8 scale_bf8(bf16x8 v, float s){
  u32x4 w = __builtin_bit_cast(u32x4, v);
  u32x4 r;
  #pragma unroll
  for (int i=0;i<4;i++){
    float lo = __uint_as_float(w[i] << 16) * s;
    float hi = __uint_as_float(w[i] & 0xffff0000u) * s;
    u32 p;
    asm("v_cvt_pk_bf16_f32 %0, %1, %2" : "=v"(p) : "v"(lo), "v"(hi));
    r[i] = p;
  }
  return __builtin_bit_cast(bf16x8, r);
}

// ---------- flash attention (r18 exact, proven 81.0 us): 128-key LDS tiles,
// 2 blocks/CU, software-pipelined tile body. ----------
__global__ __launch_bounds__(256,2) void k_attn(const u16* __restrict__ kf_g, const u16* __restrict__ vf_g,
                                                float* __restrict__ out){
  __shared__ alignas(16) u16 stg[2][16384];   // [buf][K: chunks 0..15 | V: chunks 16..31]
  const int bid  = blockIdx.x;
  const int xcd  = bid & 7;
  const int slot = bid >> 3;              // 0..63
  const int h    = (xcd<<1) | (slot>>5);  // 2 heads per XCD
  const int qt   = slot & 31;
  const int wid  = threadIdx.x >> 6;
  const int lane = threadIdx.x & 63;
  const int ql   = lane & 31;
  const int q0   = qt*128 + wid*32;
  const u16* __restrict__ Kfh = kf_g + (size_t)h*262144;
  const u16* __restrict__ Vfh = vf_g + (size_t)h*262144;
  const float SC = 0.18033688011112042f;   // log2(e)/sqrt(64)

  bf16x8 qb[4];
  #pragma unroll
  for (int ds=0; ds<4; ds++){
    bf16x8 raw = *reinterpret_cast<const bf16x8*>(&Kfh[(size_t)((q0>>5)*4 + ds)*512 + lane*8]);
    qb[ds] = scale_bf8(raw, SC);
  }

  f32x16 o0 = {}, o1 = {}, lacc = {};

  auto stage = [&](int buf, int t){
    #pragma unroll
    for (int i=0; i<8; i++){
      const int c = wid + i*4;             // 0..31, wave-uniform
      const u16* src = (c < 16)
        ? Kfh + ((size_t)(t*16 + c))*512 + lane*8
        : Vfh + ((size_t)(t*16 + c - 16))*512 + lane*8;
      __builtin_amdgcn_global_load_lds((const __attribute__((address_space(1))) void*)src,
          (__attribute__((address_space(3))) void*)(&stg[buf][(size_t)c*512]), 16, 0, 0);
    }
  };

  stage(0, 0);
  int cur = 0;
  for (int t=0; t<32; ++t){
    asm volatile("s_waitcnt vmcnt(0)" ::: "memory");
    __syncthreads();                       // tile t ready in stg[cur]
    if (t < 31) stage(cur^1, t+1);         // async prefetch next tile

    const u16* kb = &stg[cur][0];

    auto QK = [&](int ss, f32x16& p){
      bf16x8 k0 = *reinterpret_cast<const bf16x8*>(&kb[(size_t)(ss*4+0)*512 + lane*8]);
      bf16x8 k1 = *reinterpret_cast<const bf16x8*>(&kb[(size_t)(ss*4+1)*512 + lane*8]);
      bf16x8 k2 = *reinterpret_cast<const bf16x8*>(&kb[(size_t)(ss*4+2)*512 + lane*8]);
      bf16x8 k3 = *reinterpret_cast<const bf16x8*>(&kb[(size_t)(ss*4+3)*512 + lane*8]);
      f32x16 acc = {};
      acc = __builtin_amdgcn_mfma_f32_32x32x16_bf16(k0, qb[0], acc, 0,0,0);
      acc = __builtin_amdgcn_mfma_f32_32x32x16_bf16(k1, qb[1], acc, 0,0,0);
      acc = __builtin_amdgcn_mfma_f32_32x32x16_bf16(k2, qb[2], acc, 0,0,0);
      acc = __builtin_amdgcn_mfma_f32_32x32x16_bf16(k3, qb[3], acc, 0,0,0);
      p = acc;
    };
    auto SM = [&](f32x16& p, u32* pk){     // exp + lacc + pack (VALU/trans only)
      #pragma unroll
      for (int c=0; c<16; c++) p[c] = fexp2(p[c]);
      lacc += p;
      #pragma unroll
      for (int c2=0; c2<8; c2++){
        u32 a;
        asm("v_cvt_pk_bf16_f32 %0, %1, %2" : "=v"(a) : "v"(p[2*c2]), "v"(p[2*c2+1]));
        pk[c2] = a;
      }
    };
    auto PV = [&](int ss, const u32* pk){
      const int vbase = 8192 + ((ss>>1)*8 + (ss&1)*2)*512;
      bf16x8 va0 = *reinterpret_cast<const bf16x8*>(&kb[(size_t)vbase          + lane*8]);
      bf16x8 va1 = *reinterpret_cast<const bf16x8*>(&kb[(size_t)vbase +   512  + lane*8]);
      bf16x8 vb0 = *reinterpret_cast<const bf16x8*>(&kb[(size_t)vbase + 4*512  + lane*8]);
      bf16x8 vb1 = *reinterpret_cast<const bf16x8*>(&kb[(size_t)vbase + 5*512  + lane*8]);
      #pragma unroll
      for (int t2=0; t2<2; t2++){
        const int base = 4*t2;
        i32x2 r0s = __builtin_amdgcn_permlane32_swap((int)pk[base+0], (int)pk[base+2], false, false);
        i32x2 r1s = __builtin_amdgcn_permlane32_swap((int)pk[base+1], (int)pk[base+3], false, false);
        u32x4 w; w[0] = (u32)r0s[0]; w[1] = (u32)r1s[0]; w[2] = (u32)r0s[1]; w[3] = (u32)r1s[1];
        bf16x8 bt = __builtin_bit_cast(bf16x8, w);
        o0 = __builtin_amdgcn_mfma_f32_32x32x16_bf16(t2 ? va1 : va0, bt, o0, 0,0,0);
        o1 = __builtin_amdgcn_mfma_f32_32x32x16_bf16(t2 ? vb1 : vb0, bt, o1, 0,0,0);
      }
    };

    // 4 ss-steps, 1-deep software pipeline (pA/pB alternate)
    f32x16 pA, pB;
    u32 pkA[8], pkB[8];
    QK(0, pA);
    QK(1, pB);
    SM(pA, pkA);
    PV(0, pkA);
    QK(2, pA);
    SM(pB, pkB);
    PV(1, pkB);
    QK(3, pB);
    SM(pA, pkA);
    PV(2, pkA);
    SM(pB, pkB);
    PV(3, pkB);

    __syncthreads();                       // all waves done reading stg[cur]
    cur ^= 1;
  }

  float lp = (((lacc[0]+lacc[1])+(lacc[2]+lacc[3])) + ((lacc[4]+lacc[5])+(lacc[6]+lacc[7])))
           + (((lacc[8]+lacc[9])+(lacc[10]+lacc[11])) + ((lacc[12]+lacc[13])+(lacc[14]+lacc[15])));
  lp += __shfl_xor(lp, 32, 64);

  const int hi = lane >> 5;
  const float inv = 1.f / lp;
  float* orow = out + (size_t)(q0 + ql)*DMODEL + h*DKH;
  #pragma unroll
  for (int g=0; g<4; g++){
    float4 s0, s1;
    s0.x = o0[4*g+0]*inv; s0.y = o0[4*g+1]*inv; s0.z = o0[4*g+2]*inv; s0.w = o0[4*g+3]*inv;
    s1.x = o1[4*g+0]*inv; s1.y = o1[4*g+1]*inv; s1.z = o1[4*g+2]*inv; s1.w = o1[4*g+3]*inv;
    *reinterpret_cast<float4*>(&orow[      8*g + 4*hi]) = s0;
    *reinterpret_cast<float4*>(&orow[32 +  8*g + 4*hi]) = s1;
  }
}

extern "C" void kernel_launch(void* const* d_in, const int* in_sizes, int n_in,
                              void* d_out, int out_size, void* d_ws, size_t ws_size,
                              hipStream_t stream) {
  const float* X = (const float*)d_in[0];
  const float* W = (const float*)d_in[1];
  float* out = (float*)d_out;
  u16* Xb = (u16*)d_ws;                         //  8 MB
  u16* Wt = Xb + (size_t)N_TOK*DMODEL;          //  4 MB
  u16* Kf = Wt + (size_t)2*DMODEL*DMODEL;       //  8 MB fragment-major K/Q
  u16* Vf = Kf + (size_t)N_TOK*DMODEL;          //  8 MB fragment-major V^T

  k_conv <<<dim3(4608), dim3(256), 0, stream>>>(X, Xb, W, Wt);
  k_gemm <<<dim3(16,32), dim3(256), 0, stream>>>(Xb, Wt, Kf, Vf);
  k_attn <<<dim3(512), dim3(256), 0, stream>>>(Kf, Vf, out);
}